// Round 2
// baseline (159.666 us; speedup 1.0000x reference)
//
#include <hip/hip_runtime.h>
#include <hip/hip_bf16.h>

#define T 128
#define C 20
#define KQ 100
#define NT 512
#define SCALE 0.08838834764831845f   // 1/sqrt(128)
#define LDS8 136   // fp8 row stride (bytes): 34 dw == 2 mod 32 -> all accesses <=2-way (free)

typedef float  f32x4  __attribute__((ext_vector_type(4)));
typedef short  bf16x8 __attribute__((ext_vector_type(8)));
typedef unsigned int uint32;

__device__ __forceinline__ short f2bf(float f) {
    unsigned u = __builtin_bit_cast(unsigned, f);
    unsigned r = (u + 0x7FFFu + ((u >> 16) & 1u)) >> 16;   // RNE
    return (short)r;
}
__device__ __forceinline__ uint32 pk2(float a, float b) {  // v_cvt_pk_bf16_f32
    __hip_bfloat162 h = __float22bfloat162_rn(float2{a, b});
    uint32 r;
    __builtin_memcpy(&r, &h, 4);
    return r;
}
__device__ __forceinline__ int pkfp8x4(float a, float b, float c, float d) {
    int r = __builtin_amdgcn_cvt_pk_fp8_f32(a, b, 0, false);   // bytes 0,1
    r = __builtin_amdgcn_cvt_pk_fp8_f32(c, d, r, true);        // bytes 2,3
    return r;
}
__device__ __forceinline__ unsigned char fp8_1(float a) {
    return (unsigned char)(__builtin_amdgcn_cvt_pk_fp8_f32(a, 0.f, 0, false) & 0xff);
}

// ---- prep: weights -> bf16 A-fragment tiles in d_ws, BIAS FOLDED at c==20 ----
// wAll = 16 tiles x [16 ch][32 c] bf16 (k:0..6, q:7..13, v:14..15).
// Row c=20 of each tile holds the bias (x fragment supplies 1.0 there).
__global__ void prep(const float* __restrict__ Wk, const float* __restrict__ bk,
                     const float* __restrict__ Wq, const float* __restrict__ bq,
                     const float* __restrict__ Wv, const float* __restrict__ bv,
                     short* __restrict__ wkT, short* __restrict__ wqT,
                     short* __restrict__ wvT)
{
    const int t = blockIdx.x * blockDim.x + threadIdx.x;
    if (t < 112 * 32) {
        const int n = t >> 5, c = t & 31;
        float vk = 0.f, vq = 0.f;
        if (n < KQ) {
            if (c < C)       { vk = Wk[c * KQ + n]; vq = Wq[c * KQ + n]; }
            else if (c == C) { vk = bk[n];          vq = bq[n]; }
        }
        wkT[t] = f2bf(vk);
        wqT[t] = f2bf(vq);
        if (t < 32 * 32) {
            const int n2 = t >> 5, c2 = t & 31;
            float vv = 0.f;
            if (n2 < C) {
                if (c2 < C)       vv = Wv[c2 * C + n2];
                else if (c2 == C) vv = bv[n2];
            }
            wvT[t] = f2bf(vv);
        }
    }
}

// One block per batch, 512 threads, 38.3 KB LDS.
// R8-known-good structure + bias folded into weight tiles + batched weight
// fragment preloads. This round: s_setprio(1) around the scores/PV fp8-MFMA
// clusters (4 independent blocks/CU at different phases = the regime where
// setprio paid +4-7% in attn, m191), and x loads issued before LDS zero-pad.
__global__ __launch_bounds__(NT, 8) void sa_fused(
    const float* __restrict__ x,
    const short* __restrict__ wAll,
    float* __restrict__ y)
{
    __shared__ __align__(16) unsigned char kp8[T * LDS8];   // k fp8 [i][d] -> later 64*P [i][j]
    __shared__ __align__(16) unsigned char q8 [T * LDS8];   // q fp8 [j][d]
    __shared__ __align__(16) unsigned char vT8[32 * LDS8];  // v^T fp8 [dd][pos] (rows 20..31 = 0)

    const int tid  = threadIdx.x;
    const int lane = tid & 63;
    const int w    = __builtin_amdgcn_readfirstlane(tid >> 6);
    const int quad = lane >> 4;
    const int l16  = lane & 15;
    const int b    = blockIdx.x;
    const float* xb = x + (size_t)b * (T * C);

    // ---- issue x global loads FIRST (latency overlaps the LDS zero-pad) ----
    const float* xr = xb + (w * 16 + l16) * C;
    float4 f0, f1;
    f0 = (float4){0.f, 0.f, 0.f, 0.f};
    f1 = (float4){0.f, 0.f, 0.f, 0.f};
    if (quad < 2) {
        f0 = *(const float4*)(xr + quad * 8);
        f1 = *(const float4*)(xr + quad * 8 + 4);
    } else if (quad == 2) {
        f0 = *(const float4*)(xr + 16);
    }

    // ---- zero pad cols 112..127 of kp8/q8 (d-tail read by score K-loop) ----
    if (tid < T) {
        const uint2 z = {0u, 0u};
        *(uint2*)&kp8[tid * LDS8 + 112] = z;
        *(uint2*)&kp8[tid * LDS8 + 120] = z;
        *(uint2*)&q8 [tid * LDS8 + 112] = z;
        *(uint2*)&q8 [tid * LDS8 + 120] = z;
    }

    // ---- x fragment (built once): A[m=l16][k=quad*8+u] == B[k][n=l16];
    //      c pad 20->32, with c=20 element = 1.0 (bias row multiplier) ----
    bf16x8 xf;
    {
        uint32 p0 = 0, p1 = 0, p2 = 0, p3 = 0;
        if (quad < 2) {
            p0 = pk2(f0.x, f0.y); p1 = pk2(f0.z, f0.w);
            p2 = pk2(f1.x, f1.y); p3 = pk2(f1.z, f1.w);
        } else if (quad == 2) {
            p0 = pk2(f0.x, f0.y); p1 = pk2(f0.z, f0.w);
            p2 = pk2(1.f, 0.f);                       // c=20 -> 1.0 (bias row)
        }
        uint4 u4; u4.x = p0; u4.y = p1; u4.z = p2; u4.w = p3;
        xf = __builtin_bit_cast(bf16x8, u4);
    }

    // ---- projections (bf16 MFMA): wave w owns i-tile w. Weight fragments
    //      preloaded in batches of 4 (16 VGPRs) so loads pipeline. ----
    #pragma unroll
    for (int grp = 0; grp < 4; ++grp) {
        bf16x8 wfr[4];
        #pragma unroll
        for (int t = 0; t < 4; ++t)
            wfr[t] = *(const bf16x8*)(wAll + ((grp * 4 + t) * 16 + l16) * 32 + quad * 8);
        #pragma unroll
        for (int s = 0; s < 4; ++s) {
            const int tt = grp * 4 + s;
            const f32x4 cc = __builtin_amdgcn_mfma_f32_16x16x32_bf16(
                wfr[s], xf, (f32x4){0.f, 0.f, 0.f, 0.f}, 0, 0, 0);
            if (tt < 14) {                                        // k or q: ELU -> fp8 b32 write
                float e[4];
                #pragma unroll
                for (int r = 0; r < 4; ++r) {
                    const float z = cc[r];
                    e[r] = z > 0.f ? z : (__expf(z) - 1.f);
                }
                unsigned char* dst = (tt < 7)
                    ? &kp8[(w * 16 + l16) * LDS8 + tt * 16 + quad * 4]
                    : &q8 [(w * 16 + l16) * LDS8 + (tt - 7) * 16 + quad * 4];
                *(int*)dst = pkfp8x4(e[0], e[1], e[2], e[3]);
            } else {                                              // v: tanh -> vT scatter (b8)
                #pragma unroll
                for (int r = 0; r < 4; ++r) {
                    const float e2 = __expf(2.f * cc[r]);
                    vT8[((tt - 14) * 16 + quad * 4 + r) * LDS8 + w * 16 + l16]
                        = fp8_1(1.f - 2.f / (e2 + 1.f));
                }
            }
        }
    }
    __syncthreads();

    // ---- scores TRANSPOSED (fp8): S^T = q.k^T. A = q rows j (m-tile w), B = k (n=i). ----
    f32x4 acc[8];
    #pragma unroll
    for (int nt = 0; nt < 8; ++nt) acc[nt] = (f32x4){0.f, 0.f, 0.f, 0.f};
    __builtin_amdgcn_s_setprio(1);
    #pragma unroll
    for (int ks = 0; ks < 4; ++ks) {
        const long a = *(const long*)&q8[(w * 16 + l16) * LDS8 + ks * 32 + quad * 8];
        #pragma unroll
        for (int nt = 0; nt < 8; ++nt) {
            const long bk8 = *(const long*)&kp8[(nt * 16 + l16) * LDS8 + ks * 32 + quad * 8];
            acc[nt] = __builtin_amdgcn_mfma_f32_16x16x32_fp8_fp8(a, bk8, acc[nt], 0, 0, 0);
        }
    }
    __builtin_amdgcn_s_setprio(0);

    // ---- softmax over i (axis=1), in registers ----
    // Thread holds (j = w*16+quad*4+r, i = nt*16+l16). Sum over i = nt-sum + l16 butterfly.
    float ssum[4] = {0.f, 0.f, 0.f, 0.f};
    #pragma unroll
    for (int nt = 0; nt < 8; ++nt)
        #pragma unroll
        for (int r = 0; r < 4; ++r) {
            const float e = __expf(acc[nt][r] * SCALE);
            acc[nt][r] = e;
            ssum[r] += e;
        }
    #pragma unroll
    for (int r = 0; r < 4; ++r) {
        float s = ssum[r];
        s += __shfl_xor(s, 1); s += __shfl_xor(s, 2);
        s += __shfl_xor(s, 4); s += __shfl_xor(s, 8);
        ssum[r] = 64.f / s;                                       // 64*linv[j] (fp8 range lift)
    }
    __syncthreads();                                              // all score reads of kp8/q8 done

    // ---- write 64*P[i][j] fp8 (b32: 4 consecutive j per thread) over k ----
    #pragma unroll
    for (int nt = 0; nt < 8; ++nt) {
        *(int*)&kp8[(nt * 16 + l16) * LDS8 + w * 16 + quad * 4]
            = pkfp8x4(acc[nt][0] * ssum[0], acc[nt][1] * ssum[1],
                      acc[nt][2] * ssum[2], acc[nt][3] * ssum[3]);
    }
    __syncthreads();

    // ---- PV (fp8): A = 64P (m-tile w, K = j = 128), B = v^T (N = 32) ----
    f32x4 yacc[2];
    yacc[0] = (f32x4){0.f, 0.f, 0.f, 0.f};
    yacc[1] = (f32x4){0.f, 0.f, 0.f, 0.f};
    __builtin_amdgcn_s_setprio(1);
    #pragma unroll
    for (int ks = 0; ks < 4; ++ks) {
        const long a = *(const long*)&kp8[(w * 16 + l16) * LDS8 + ks * 32 + quad * 8];
        #pragma unroll
        for (int nt = 0; nt < 2; ++nt) {
            const long bv8 = *(const long*)&vT8[(nt * 16 + l16) * LDS8 + ks * 32 + quad * 8];
            yacc[nt] = __builtin_amdgcn_mfma_f32_16x16x32_fp8_fp8(a, bv8, yacc[nt], 0, 0, 0);
        }
    }
    __builtin_amdgcn_s_setprio(0);

    // ---- epilogue: y = PV/64 + x (direct stores, R8-known-good) ----
    {
        float* yb = y + (size_t)b * (T * C);
        const float inv64 = 1.f / 64.f;
        #pragma unroll
        for (int r = 0; r < 4; ++r) {
            const int row  = w * 16 + quad * 4 + r;
            const int base = row * C;
            yb[base + l16] = yacc[0][r] * inv64 + xb[base + l16];
            if (l16 < 4)
                yb[base + 16 + l16] = yacc[1][r] * inv64 + xb[base + 16 + l16];
        }
    }
}

extern "C" void kernel_launch(void* const* d_in, const int* in_sizes, int n_in,
                              void* d_out, int out_size, void* d_ws, size_t ws_size,
                              hipStream_t stream) {
    const float* x  = (const float*)d_in[0];
    const float* Wk = (const float*)d_in[1];
    const float* bk = (const float*)d_in[2];
    const float* Wq = (const float*)d_in[3];
    const float* bq = (const float*)d_in[4];
    const float* Wv = (const float*)d_in[5];
    const float* bv = (const float*)d_in[6];
    float* y = (float*)d_out;

    char* ws = (char*)d_ws;
    short* wkT = (short*)ws;                 // tiles 0..6   [112][32] bf16 (bias at c=20)
    short* wqT = (short*)(ws + 7168);        // tiles 7..13  [112][32] bf16
    short* wvT = (short*)(ws + 14336);       // tiles 14..15 [32][32]  bf16

    prep<<<14, 256, 0, stream>>>(Wk, bk, Wq, bq, Wv, bv, wkT, wqT, wvT);

    const int B = in_sizes[0] / (T * C);     // 4096
    sa_fused<<<B, NT, 0, stream>>>(x, (const short*)ws, y);
}